// Round 12
// baseline (714.019 us; speedup 1.0000x reference)
//
#include <hip/hip_runtime.h>
#include <hip/hip_fp16.h>

#define NEG_SLOPE 0.2f
#define BSH 9                    // bucket = dst >> 9  (512 nodes / bucket)
#define NBUCK 256                // covers dst < 131072
#define NB1 256                  // count/place blocks
#define DCAP 11264               // pass D LDS staging capacity (uints); mean bucket ~8.7k, 27 sigma margin
#define NREP 32                  // pool replicas

typedef _Float16 f16;
typedef __attribute__((ext_vector_type(8))) _Float16 half8;
typedef __attribute__((ext_vector_type(4))) _Float16 half4;
typedef __attribute__((ext_vector_type(4))) float f32x4;

// ============================ Kernel A: prep_w ∥ bucket_count ∥ zero accumulators ============================
// blocks 0..63: W1 transpose cols 2b,2b+1 -> W1t fp16 [c][k]
// blocks 64..95: W2 transpose -> W2t
// blocks 96..351: bucket histogram (also zero poolrep/cntrep slices)
__global__ __launch_bounds__(256) void kernelA(
    const float* __restrict__ W1, const float* __restrict__ W2,
    f16* __restrict__ W1t, f16* __restrict__ W2t,
    const int* __restrict__ ei, int* __restrict__ cntg,
    float* __restrict__ zbase, int nz, int E, int Ep, int chunk)
{
    __shared__ int lc[NBUCK];
    int b = blockIdx.x, t = threadIdx.x;
    if (b < 64) {
        int k = t & 127, c = 2 * b + (t >> 7);
        W1t[c * 128 + k] = (f16)W1[k * 128 + c];
        return;
    }
    if (b < 96) {
        int k = t & 127, c = 2 * (b - 64) + (t >> 7);
        W2t[c * 128 + k] = (f16)W2[k * 64 + c];
        return;
    }
    int i = b - 96;
    // zero a slice of the replica accumulators
    int per = (nz + NB1 - 1) / NB1;
    for (int z = i * per + t; z < min((i + 1) * per, nz); z += 256) zbase[z] = 0.f;
    lc[t] = 0;
    __syncthreads();
    int e0 = i * chunk, e1 = min(e0 + chunk, Ep);
    for (int e = e0 + t; e < e1; e += 256) {
        int dst = (e < E) ? ei[E + e] : e - E;
        atomicAdd(&lc[dst >> BSH], 1);
    }
    __syncthreads();
    cntg[i * NBUCK + t] = lc[t];
}

// ============================ Pass B1: per-bucket scan over chunk-blocks ============================
__global__ __launch_bounds__(256) void bucket_scan_t(
    const int* __restrict__ cntg, int* __restrict__ offs, int* __restrict__ tot)
{
    __shared__ int sh[256];
    int b = blockIdx.x, i = threadIdx.x;
    int v = cntg[i * NBUCK + b];
    sh[i] = v;
    __syncthreads();
    for (int off = 1; off < 256; off <<= 1) {
        int u = (i >= off) ? sh[i - off] : 0;
        __syncthreads();
        sh[i] += u;
        __syncthreads();
    }
    offs[i * NBUCK + b] = sh[i] - v;
    if (i == 255) tot[b] = sh[255];
}

// ============================ Pass C: place packed pairs via LDS cursors ============================
__global__ __launch_bounds__(256) void bucket_place(
    const int* __restrict__ ei, const int* __restrict__ offs, const int* __restrict__ tot,
    unsigned* __restrict__ pairs, int E, int Ep, int chunk)
{
    __shared__ int cur[NBUCK];
    __shared__ int sh[256];
    int i = blockIdx.x, t = threadIdx.x;
    int v = tot[t];
    sh[t] = v;
    __syncthreads();
    for (int off = 1; off < 256; off <<= 1) {
        int u = (t >= off) ? sh[t - off] : 0;
        __syncthreads();
        sh[t] += u;
        __syncthreads();
    }
    cur[t] = offs[i * NBUCK + t] + sh[t] - v;
    __syncthreads();
    int e0 = i * chunk, e1 = min(e0 + chunk, Ep);
    for (int e = e0 + t; e < e1; e += 256) {
        int src, dst;
        if (e < E) { src = ei[e]; dst = ei[E + e]; } else { src = dst = e - E; }
        int pos = atomicAdd(&cur[dst >> BSH], 1);
        pairs[pos] = ((unsigned)(dst & 511) << 17) | (unsigned)src;
    }
}

// ============================ Kernel B: bucket_build ∥ gemm1 (MFMA) ============================
// blocks 0..255: CSR finalize per bucket. blocks 256..: gemm1 64-row tiles.
// LDS union: build = 1280 ints + DCAP uints = 50.2KB; gemm = 26112 halves = 52.2KB.
#define SMEM_BYTES 52224
__global__ __launch_bounds__(256) void kernelB(
    const unsigned* __restrict__ pairs, const int* __restrict__ tot,
    int* __restrict__ rowStart, int* __restrict__ deg, int* __restrict__ srcS,
    const float* __restrict__ x, const f16* __restrict__ W1t,
    const float* __restrict__ a1s_vec, const float* __restrict__ a1d_vec,
    f16* __restrict__ h1h, float* __restrict__ a1s, float* __restrict__ a1d, int N)
{
    __shared__ char smem[SMEM_BYTES];
    int t = threadIdx.x;

    if (blockIdx.x < NBUCK) {
        // ---- bucket_build ----
        int* ucnt = (int*)smem;                    // 512
        int* ustart = ucnt + 512;                  // 512
        int* sh = ustart + 512;                    // 256
        unsigned* stage = (unsigned*)(sh + 256);   // DCAP
        int b = blockIdx.x;
        int node0 = b << BSH;
        if (node0 >= N) return;
        ucnt[t] = 0; ucnt[t + 256] = 0;
        int v = tot[t];
        sh[t] = v;
        __syncthreads();
        for (int off = 1; off < 256; off <<= 1) {
            int u = (t >= off) ? sh[t - off] : 0;
            __syncthreads();
            sh[t] += u;
            __syncthreads();
        }
        int s0 = (b == 0) ? 0 : sh[b - 1];
        int s1 = sh[b];
        int cnt = s1 - s0;
        __syncthreads();
        bool fit = (cnt <= DCAP);
        for (int k = t; k < cnt; k += 256) {
            unsigned pv = pairs[s0 + k];
            if (fit) stage[k] = pv;
            atomicAdd(&ucnt[pv >> 17], 1);
        }
        __syncthreads();
        int a0 = ucnt[2 * t], a1 = ucnt[2 * t + 1];
        int s2 = a0 + a1;
        sh[t] = s2;
        __syncthreads();
        for (int off = 1; off < 256; off <<= 1) {
            int u = (t >= off) ? sh[t - off] : 0;
            __syncthreads();
            sh[t] += u;
            __syncthreads();
        }
        int exc = sh[t] - s2;
        ustart[2 * t] = exc;
        ustart[2 * t + 1] = exc + a0;
        __syncthreads();
        for (int l = t; l < 512; l += 256) {
            int node = node0 + l;
            if (node < N) { rowStart[node] = s0 + ustart[l]; deg[node] = ucnt[l]; }
        }
        __syncthreads();
        for (int k = t; k < cnt; k += 256) {
            unsigned pv = fit ? stage[k] : pairs[s0 + k];
            int pos = atomicAdd(&ustart[pv >> 17], 1);
            srcS[s0 + pos] = (int)(pv & 131071u);
        }
        return;
    }

    // ---- gemm1: h1h = fp16(x @ W1), 64 rows x 128 cols ----
    f16* Ash = (f16*)smem;                         // [64][136]
    f16* Bsh = Ash + 64 * 136;                     // [128][136]
    int row0 = (blockIdx.x - NBUCK) << 6;

    #pragma unroll
    for (int c = 0; c < 8; ++c) {
        int l = c * 256 + t;
        int r = l >> 5, f = l & 31;
        int rr = row0 + r;
        float4 v = {0.f, 0.f, 0.f, 0.f};
        if (rr < N) v = *(const float4*)&x[(size_t)rr * 128 + f * 4];
        half4 hv = {(f16)v.x, (f16)v.y, (f16)v.z, (f16)v.w};
        *(half4*)&Ash[r * 136 + f * 4] = hv;
    }
    #pragma unroll
    for (int c = 0; c < 8; ++c) {
        int l = c * 256 + t;
        int row = l >> 4, f = l & 15;
        *(half8*)&Bsh[row * 136 + f * 8] = *(const half8*)&W1t[row * 128 + f * 8];
    }
    __syncthreads();

    int lane = t & 63, w = t >> 6;
    int lr = lane & 15, kg = lane >> 4;
    f32x4 acc[8];
    #pragma unroll
    for (int ct = 0; ct < 8; ++ct) acc[ct] = (f32x4){0.f, 0.f, 0.f, 0.f};

    #pragma unroll
    for (int kt = 0; kt < 4; ++kt) {
        half8 af = *(const half8*)&Ash[(w * 16 + lr) * 136 + kt * 32 + kg * 8];
        #pragma unroll
        for (int ct = 0; ct < 8; ++ct) {
            half8 bf = *(const half8*)&Bsh[(ct * 16 + lr) * 136 + kt * 32 + kg * 8];
            acc[ct] = __builtin_amdgcn_mfma_f32_16x16x32_f16(af, bf, acc[ct], 0, 0, 0);
        }
    }

    #pragma unroll
    for (int reg = 0; reg < 4; ++reg) {
        float ps0 = 0.f, pd0 = 0.f, ps1 = 0.f, pd1 = 0.f;
        #pragma unroll
        for (int ct = 0; ct < 4; ++ct) {
            float a = acc[ct][reg];
            ps0 += a * a1s_vec[ct * 16 + lr];
            pd0 += a * a1d_vec[ct * 16 + lr];
        }
        #pragma unroll
        for (int ct = 4; ct < 8; ++ct) {
            float a = acc[ct][reg];
            ps1 += a * a1s_vec[ct * 16 + lr];
            pd1 += a * a1d_vec[ct * 16 + lr];
        }
        #pragma unroll
        for (int o = 1; o <= 8; o <<= 1) {
            ps0 += __shfl_xor(ps0, o); pd0 += __shfl_xor(pd0, o);
            ps1 += __shfl_xor(ps1, o); pd1 += __shfl_xor(pd1, o);
        }
        if (lr == 0) {
            int rr = row0 + w * 16 + kg * 4 + reg;
            if (rr < N) {
                a1s[rr * 2] = ps0; a1d[rr * 2] = pd0;
                a1s[rr * 2 + 1] = ps1; a1d[rr * 2 + 1] = pd1;
            }
        }
    }

    __syncthreads();
    #pragma unroll
    for (int ct = 0; ct < 8; ++ct)
        #pragma unroll
        for (int reg = 0; reg < 4; ++reg)
            Ash[(w * 16 + kg * 4 + reg) * 136 + ct * 16 + lr] = (f16)acc[ct][reg];
    __syncthreads();
    #pragma unroll
    for (int c = 0; c < 4; ++c) {
        int l = c * 256 + t;
        int r = l >> 4, f = l & 15;
        int rr = row0 + r;
        if (rr < N) *(half8*)&h1h[(size_t)rr * 128 + f * 8] = *(const half8*)&Ash[r * 136 + f * 8];
    }
}

// ============================ Fused softmax+aggregate, layer 1 ============================
__global__ __launch_bounds__(256) void fused_aggr1(
    const int* __restrict__ rowStart, const int* __restrict__ deg, const int* __restrict__ srcS,
    const float* __restrict__ a1s, const float* __restrict__ a1d, const float* __restrict__ b1,
    const f16* __restrict__ h1h, f16* __restrict__ out1h, int N)
{
    int lane = threadIdx.x & 63;
    int dst = blockIdx.x * 4 + (threadIdx.x >> 6);
    if (dst >= N) return;
    int base = rowStart[dst];
    int d = deg[dst];
    float ad0 = a1d[2 * dst], ad1 = a1d[2 * dst + 1];
    int tx = lane & 15, j2 = lane >> 4;
    float acc[8] = {};
    float dpart0 = 0.f, dpart1 = 0.f;

    for (int c0 = 0; c0 < d; c0 += 64) {
        int cn = min(64, d - c0);
        int s = 0; float p0 = 0.f, p1 = 0.f;
        if (lane < cn) {
            s = srcS[base + c0 + lane];
            float2 av = *(const float2*)&a1s[2 * s];
            float e0 = av.x + ad0, e1 = av.y + ad1;
            e0 = e0 > 0.f ? e0 : NEG_SLOPE * e0;
            e1 = e1 > 0.f ? e1 : NEG_SLOPE * e1;
            p0 = __expf(e0); p1 = __expf(e1);
        }
        dpart0 += p0; dpart1 += p1;
        int niter = (cn + 3) >> 2;
        #pragma unroll 4
        for (int jj = 0; jj < niter; ++jj) {
            int esub = jj * 4 + j2;
            int   sj = __shfl(s, esub);
            float q0 = __shfl(p0, esub);
            float q1 = __shfl(p1, esub);
            float q  = (tx < 8) ? q0 : q1;
            half8 v = *(const half8*)&h1h[(size_t)sj * 128 + tx * 8];
            #pragma unroll
            for (int k = 0; k < 8; ++k) acc[k] += q * (float)v[k];
        }
    }
    #pragma unroll
    for (int k = 0; k < 8; ++k) acc[k] += __shfl_xor(acc[k], 16);
    #pragma unroll
    for (int k = 0; k < 8; ++k) acc[k] += __shfl_xor(acc[k], 32);
    #pragma unroll
    for (int o = 32; o; o >>= 1) { dpart0 += __shfl_xor(dpart0, o); dpart1 += __shfl_xor(dpart1, o); }
    if (j2 == 0) {
        float iv = (tx < 8) ? (1.f / dpart0) : (1.f / dpart1);
        float4 blo = *(const float4*)&b1[tx * 8];
        float4 bhi = *(const float4*)&b1[tx * 8 + 4];
        float o0 = fmaxf(acc[0] * iv + blo.x, 0.f);
        float o1 = fmaxf(acc[1] * iv + blo.y, 0.f);
        float o2 = fmaxf(acc[2] * iv + blo.z, 0.f);
        float o3 = fmaxf(acc[3] * iv + blo.w, 0.f);
        float o4 = fmaxf(acc[4] * iv + bhi.x, 0.f);
        float o5 = fmaxf(acc[5] * iv + bhi.y, 0.f);
        float o6 = fmaxf(acc[6] * iv + bhi.z, 0.f);
        float o7 = fmaxf(acc[7] * iv + bhi.w, 0.f);
        half8 hv = {(f16)o0, (f16)o1, (f16)o2, (f16)o3, (f16)o4, (f16)o5, (f16)o6, (f16)o7};
        *(half8*)&out1h[(size_t)dst * 128 + tx * 8] = hv;
    }
}

// ============================ GEMM 2 (MFMA) ============================
__global__ __launch_bounds__(256) void gemm2_kernel(
    const f16* __restrict__ out1h, const f16* __restrict__ W2t,
    const float* __restrict__ a2s_vec, const float* __restrict__ a2d_vec,
    f16* __restrict__ h2h, float* __restrict__ a2s, float* __restrict__ a2d, int N)
{
    __shared__ f16 Ash[64 * 136];
    __shared__ f16 Bsh[64 * 136];
    int t = threadIdx.x;
    int row0 = blockIdx.x << 6;

    #pragma unroll
    for (int c = 0; c < 4; ++c) {
        int l = c * 256 + t;
        int r = l >> 4, f = l & 15;
        int rr = row0 + r;
        half8 hv = {0, 0, 0, 0, 0, 0, 0, 0};
        if (rr < N) hv = *(const half8*)&out1h[(size_t)rr * 128 + f * 8];
        *(half8*)&Ash[r * 136 + f * 8] = hv;
    }
    #pragma unroll
    for (int c = 0; c < 4; ++c) {
        int l = c * 256 + t;
        int row = l >> 4, f = l & 15;
        *(half8*)&Bsh[row * 136 + f * 8] = *(const half8*)&W2t[row * 128 + f * 8];
    }
    __syncthreads();

    int lane = t & 63, w = t >> 6;
    int lr = lane & 15, kg = lane >> 4;
    f32x4 acc[4];
    #pragma unroll
    for (int ct = 0; ct < 4; ++ct) acc[ct] = (f32x4){0.f, 0.f, 0.f, 0.f};

    #pragma unroll
    for (int kt = 0; kt < 4; ++kt) {
        half8 af = *(const half8*)&Ash[(w * 16 + lr) * 136 + kt * 32 + kg * 8];
        #pragma unroll
        for (int ct = 0; ct < 4; ++ct) {
            half8 bf = *(const half8*)&Bsh[(ct * 16 + lr) * 136 + kt * 32 + kg * 8];
            acc[ct] = __builtin_amdgcn_mfma_f32_16x16x32_f16(af, bf, acc[ct], 0, 0, 0);
        }
    }

    #pragma unroll
    for (int reg = 0; reg < 4; ++reg) {
        float ps = 0.f, pd = 0.f;
        #pragma unroll
        for (int ct = 0; ct < 4; ++ct) {
            float a = acc[ct][reg];
            ps += a * a2s_vec[ct * 16 + lr];
            pd += a * a2d_vec[ct * 16 + lr];
        }
        #pragma unroll
        for (int o = 1; o <= 8; o <<= 1) { ps += __shfl_xor(ps, o); pd += __shfl_xor(pd, o); }
        if (lr == 0) {
            int rr = row0 + w * 16 + kg * 4 + reg;
            if (rr < N) { a2s[rr] = ps; a2d[rr] = pd; }
        }
    }

    __syncthreads();
    #pragma unroll
    for (int ct = 0; ct < 4; ++ct)
        #pragma unroll
        for (int reg = 0; reg < 4; ++reg)
            Ash[(w * 16 + kg * 4 + reg) * 136 + ct * 16 + lr] = (f16)acc[ct][reg];
    __syncthreads();
    #pragma unroll
    for (int c = 0; c < 2; ++c) {
        int l = c * 256 + t;
        int r = l >> 3, f = l & 7;
        int rr = row0 + r;
        if (rr < N) *(half8*)&h2h[(size_t)rr * 64 + f * 8] = *(const half8*)&Ash[r * 136 + f * 8];
    }
}

// ============================ Fused aggr2 + relu(b2) + pooling into replicas ============================
__global__ __launch_bounds__(256) void fused_aggr2(
    const int* __restrict__ rowStart, const int* __restrict__ deg, const int* __restrict__ srcS,
    const float* __restrict__ a2s, const float* __restrict__ a2d, const float* __restrict__ b2,
    const f16* __restrict__ h2h, const int* __restrict__ batch,
    float* __restrict__ poolrep, float* __restrict__ cntrep, int N)
{
    int lane = threadIdx.x & 63;
    int dst = blockIdx.x * 4 + (threadIdx.x >> 6);
    if (dst >= N) return;
    int base = rowStart[dst];
    int d = deg[dst];
    float ad = a2d[dst];
    int tx = lane & 7, j3 = lane >> 3;
    float acc[8] = {};
    float dpart = 0.f;

    for (int c0 = 0; c0 < d; c0 += 64) {
        int cn = min(64, d - c0);
        int s = 0; float p = 0.f;
        if (lane < cn) {
            s = srcS[base + c0 + lane];
            float e = a2s[s] + ad;
            e = e > 0.f ? e : NEG_SLOPE * e;
            p = __expf(e);
        }
        dpart += p;
        int niter = (cn + 7) >> 3;
        #pragma unroll 4
        for (int jj = 0; jj < niter; ++jj) {
            int esub = jj * 8 + j3;
            int   sj = __shfl(s, esub);
            float q  = __shfl(p, esub);
            half8 v = *(const half8*)&h2h[(size_t)sj * 64 + tx * 8];
            #pragma unroll
            for (int k = 0; k < 8; ++k) acc[k] += q * (float)v[k];
        }
    }
    #pragma unroll
    for (int k = 0; k < 8; ++k) acc[k] += __shfl_xor(acc[k], 8);
    #pragma unroll
    for (int k = 0; k < 8; ++k) acc[k] += __shfl_xor(acc[k], 16);
    #pragma unroll
    for (int k = 0; k < 8; ++k) acc[k] += __shfl_xor(acc[k], 32);
    #pragma unroll
    for (int o = 32; o; o >>= 1) dpart += __shfl_xor(dpart, o);
    if (j3 == 0) {
        float iv = 1.f / dpart;
        float4 blo = *(const float4*)&b2[tx * 8];
        float4 bhi = *(const float4*)&b2[tx * 8 + 4];
        float o_[8];
        o_[0] = fmaxf(acc[0] * iv + blo.x, 0.f);
        o_[1] = fmaxf(acc[1] * iv + blo.y, 0.f);
        o_[2] = fmaxf(acc[2] * iv + blo.z, 0.f);
        o_[3] = fmaxf(acc[3] * iv + blo.w, 0.f);
        o_[4] = fmaxf(acc[4] * iv + bhi.x, 0.f);
        o_[5] = fmaxf(acc[5] * iv + bhi.y, 0.f);
        o_[6] = fmaxf(acc[6] * iv + bhi.z, 0.f);
        o_[7] = fmaxf(acc[7] * iv + bhi.w, 0.f);
        int g = batch[dst];
        float* pb = &poolrep[(blockIdx.x & (NREP - 1)) * (64 * 64) + g * 64 + tx * 8];
        #pragma unroll
        for (int k = 0; k < 8; ++k) atomicAdd(&pb[k], o_[k]);
        if (tx == 0) atomicAdd(&cntrep[(blockIdx.x & (NREP - 1)) * 64 + g], 1.0f);
    }
}

// ============================ Final: reduce replicas + linear ============================
// block = graph g, one wave; lane = channel.
__global__ __launch_bounds__(64) void final_kernel(
    const float* __restrict__ poolrep, const float* __restrict__ cntrep,
    const float* __restrict__ Wlin, const float* __restrict__ blin,
    float* __restrict__ out, int G)
{
    int g = blockIdx.x, c = threadIdx.x;
    float s = 0.f;
    #pragma unroll
    for (int r = 0; r < NREP; ++r) s += poolrep[r * (64 * 64) + g * 64 + c];
    s *= Wlin[c];
    #pragma unroll
    for (int o = 32; o; o >>= 1) s += __shfl_xor(s, o);
    if (c == 0) {
        float cn = 0.f;
        #pragma unroll
        for (int r = 0; r < NREP; ++r) cn += cntrep[r * 64 + g];
        cn = cn > 1.f ? cn : 1.f;
        out[g] = s / cn + blin[0];
    }
}

extern "C" void kernel_launch(void* const* d_in, const int* in_sizes, int n_in,
                              void* d_out, int out_size, void* d_ws, size_t ws_size,
                              hipStream_t stream) {
    const float* x     = (const float*)d_in[0];
    const int*   ei    = (const int*)d_in[1];
    const int*   batch = (const int*)d_in[2];
    const float* W1    = (const float*)d_in[3];
    const float* a1sv  = (const float*)d_in[4];
    const float* a1dv  = (const float*)d_in[5];
    const float* b1    = (const float*)d_in[6];
    const float* W2    = (const float*)d_in[7];
    const float* a2sv  = (const float*)d_in[8];
    const float* a2dv  = (const float*)d_in[9];
    const float* b2    = (const float*)d_in[10];
    const float* Wlin  = (const float*)d_in[11];
    const float* blin  = (const float*)d_in[12];

    int N  = in_sizes[2];
    int E  = in_sizes[1] / 2;
    int Ep = E + N;
    const int G = 64;
    int chunk = (Ep + NB1 - 1) / NB1;

    float* ws = (float*)d_ws;
    size_t off = 0;
    f16*  out1h = (f16*)(ws + off); off += (size_t)N * 64;   // N*128 halves
    f16*  h1h   = (f16*)(ws + off); off += (size_t)N * 64;   // N*128 halves
    f16*  h2h   = (f16*)(ws + off); off += (size_t)N * 32;   // N*64 halves
    float* a1s  = ws + off; off += (size_t)N * 2;
    float* a1d  = ws + off; off += (size_t)N * 2;
    float* a2s  = ws + off; off += N;
    float* a2d  = ws + off; off += N;
    int* degA   = (int*)(ws + off); off += N;
    int* rowStart = (int*)(ws + off); off += N;
    int* cntg   = (int*)(ws + off); off += NB1 * NBUCK;
    int* offs   = (int*)(ws + off); off += NB1 * NBUCK;
    int* tot    = (int*)(ws + off); off += NBUCK;
    unsigned* pairs = (unsigned*)(ws + off); off += Ep;
    int* srcS   = (int*)(ws + off); off += Ep;
    float* poolrep = ws + off; off += NREP * 64 * 64;
    float* cntrep  = ws + off; off += NREP * 64;
    f16* W1t    = (f16*)(ws + off); off += 128 * 64;         // 128*128 halves
    f16* W2t    = (f16*)(ws + off); off += 64 * 64;          // 64*128 halves

    int nzero = NREP * 64 * 64 + NREP * 64;   // poolrep + cntrep (contiguous)

    // A: W transposes ∥ bucket histogram ∥ zero replica accumulators
    kernelA<<<96 + NB1, 256, 0, stream>>>(W1, W2, W1t, W2t, ei, cntg, poolrep, nzero, E, Ep, chunk);
    bucket_scan_t<<<NBUCK, 256, 0, stream>>>(cntg, offs, tot);
    bucket_place<<<NB1, 256, 0, stream>>>(ei, offs, tot, pairs, E, Ep, chunk);
    // B: CSR finalize (blocks 0..255) ∥ gemm1 (rest)
    kernelB<<<NBUCK + (N + 63) / 64, 256, 0, stream>>>(
        pairs, tot, rowStart, degA, srcS,
        x, W1t, a1sv, a1dv, h1h, a1s, a1d, N);
    fused_aggr1<<<(N + 3) / 4, 256, 0, stream>>>(rowStart, degA, srcS, a1s, a1d, b1, h1h, out1h, N);
    gemm2_kernel<<<(N + 63) / 64, 256, 0, stream>>>(out1h, W2t, a2sv, a2dv, h2h, a2s, a2d, N);
    fused_aggr2<<<(N + 3) / 4, 256, 0, stream>>>(rowStart, degA, srcS, a2s, a2d, b2, h2h, batch, poolrep, cntrep, N);
    final_kernel<<<G, 64, 0, stream>>>(poolrep, cntrep, Wlin, blin, (float*)d_out, G);
}

// Round 13
// 241.302 us; speedup vs baseline: 2.9590x; 2.9590x over previous
//
#include <hip/hip_runtime.h>
#include <hip/hip_fp16.h>

#define NEG_SLOPE 0.2f
#define BSH 9                    // bucket = dst >> 9  (512 nodes / bucket)
#define NBUCK 256                // covers dst < 131072
#define NB1 256                  // count/place blocks
#define DCAP 11264               // bucket_build LDS staging capacity (uints)

typedef _Float16 f16;
typedef __attribute__((ext_vector_type(8))) _Float16 half8;
typedef __attribute__((ext_vector_type(4))) _Float16 half4;
typedef __attribute__((ext_vector_type(4))) float f32x4;

// ============================ Kernel A: prep_w ∥ bucket_count ∥ zero pool ============================
__global__ __launch_bounds__(256) void kernelA(
    const float* __restrict__ W1, const float* __restrict__ W2,
    f16* __restrict__ W1t, f16* __restrict__ W2t,
    const int* __restrict__ ei, int* __restrict__ cntg,
    float* __restrict__ zbase, int nz, int E, int Ep, int chunk)
{
    __shared__ int lc[NBUCK];
    int b = blockIdx.x, t = threadIdx.x;
    if (b < 64) {
        int k = t & 127, c = 2 * b + (t >> 7);
        W1t[c * 128 + k] = (f16)W1[k * 128 + c];
        return;
    }
    if (b < 96) {
        int k = t & 127, c = 2 * (b - 64) + (t >> 7);
        W2t[c * 128 + k] = (f16)W2[k * 64 + c];
        return;
    }
    int i = b - 96;
    if (i == 0) for (int z = t; z < nz; z += 256) zbase[z] = 0.f;
    lc[t] = 0;
    __syncthreads();
    int e0 = i * chunk, e1 = min(e0 + chunk, Ep);
    for (int e = e0 + t; e < e1; e += 256) {
        int dst = (e < E) ? ei[E + e] : e - E;
        atomicAdd(&lc[dst >> BSH], 1);
    }
    __syncthreads();
    cntg[i * NBUCK + t] = lc[t];
}

// ============================ Pass B1: per-bucket scan over chunk-blocks ============================
__global__ __launch_bounds__(256) void bucket_scan_t(
    const int* __restrict__ cntg, int* __restrict__ offs, int* __restrict__ tot)
{
    __shared__ int sh[256];
    int b = blockIdx.x, i = threadIdx.x;
    int v = cntg[i * NBUCK + b];
    sh[i] = v;
    __syncthreads();
    for (int off = 1; off < 256; off <<= 1) {
        int u = (i >= off) ? sh[i - off] : 0;
        __syncthreads();
        sh[i] += u;
        __syncthreads();
    }
    offs[i * NBUCK + b] = sh[i] - v;
    if (i == 255) tot[b] = sh[255];
}

// ============================ Pass C: place packed pairs via LDS cursors ============================
__global__ __launch_bounds__(256) void bucket_place(
    const int* __restrict__ ei, const int* __restrict__ offs, const int* __restrict__ tot,
    unsigned* __restrict__ pairs, int E, int Ep, int chunk)
{
    __shared__ int cur[NBUCK];
    __shared__ int sh[256];
    int i = blockIdx.x, t = threadIdx.x;
    int v = tot[t];
    sh[t] = v;
    __syncthreads();
    for (int off = 1; off < 256; off <<= 1) {
        int u = (t >= off) ? sh[t - off] : 0;
        __syncthreads();
        sh[t] += u;
        __syncthreads();
    }
    cur[t] = offs[i * NBUCK + t] + sh[t] - v;
    __syncthreads();
    int e0 = i * chunk, e1 = min(e0 + chunk, Ep);
    for (int e = e0 + t; e < e1; e += 256) {
        int src, dst;
        if (e < E) { src = ei[e]; dst = ei[E + e]; } else { src = dst = e - E; }
        int pos = atomicAdd(&cur[dst >> BSH], 1);
        pairs[pos] = ((unsigned)(dst & 511) << 17) | (unsigned)src;
    }
}

// ============================ Kernel B: bucket_build ∥ gemm1 (MFMA) ============================
#define SMEM_BYTES 52224
__global__ __launch_bounds__(256) void kernelB(
    const unsigned* __restrict__ pairs, const int* __restrict__ tot,
    int* __restrict__ rowStart, int* __restrict__ deg, int* __restrict__ srcS,
    const float* __restrict__ x, const f16* __restrict__ W1t,
    const float* __restrict__ a1s_vec, const float* __restrict__ a1d_vec,
    f16* __restrict__ h1h, float* __restrict__ a1s, float* __restrict__ a1d, int N)
{
    __shared__ char smem[SMEM_BYTES];
    int t = threadIdx.x;

    if (blockIdx.x < NBUCK) {
        int* ucnt = (int*)smem;
        int* ustart = ucnt + 512;
        int* sh = ustart + 512;
        unsigned* stage = (unsigned*)(sh + 256);
        int b = blockIdx.x;
        int node0 = b << BSH;
        if (node0 >= N) return;
        ucnt[t] = 0; ucnt[t + 256] = 0;
        int v = tot[t];
        sh[t] = v;
        __syncthreads();
        for (int off = 1; off < 256; off <<= 1) {
            int u = (t >= off) ? sh[t - off] : 0;
            __syncthreads();
            sh[t] += u;
            __syncthreads();
        }
        int s0 = (b == 0) ? 0 : sh[b - 1];
        int s1 = sh[b];
        int cnt = s1 - s0;
        __syncthreads();
        bool fit = (cnt <= DCAP);
        for (int k = t; k < cnt; k += 256) {
            unsigned pv = pairs[s0 + k];
            if (fit) stage[k] = pv;
            atomicAdd(&ucnt[pv >> 17], 1);
        }
        __syncthreads();
        int a0 = ucnt[2 * t], a1 = ucnt[2 * t + 1];
        int s2 = a0 + a1;
        sh[t] = s2;
        __syncthreads();
        for (int off = 1; off < 256; off <<= 1) {
            int u = (t >= off) ? sh[t - off] : 0;
            __syncthreads();
            sh[t] += u;
            __syncthreads();
        }
        int exc = sh[t] - s2;
        ustart[2 * t] = exc;
        ustart[2 * t + 1] = exc + a0;
        __syncthreads();
        for (int l = t; l < 512; l += 256) {
            int node = node0 + l;
            if (node < N) { rowStart[node] = s0 + ustart[l]; deg[node] = ucnt[l]; }
        }
        __syncthreads();
        for (int k = t; k < cnt; k += 256) {
            unsigned pv = fit ? stage[k] : pairs[s0 + k];
            int pos = atomicAdd(&ustart[pv >> 17], 1);
            srcS[s0 + pos] = (int)(pv & 131071u);
        }
        return;
    }

    // ---- gemm1: h1h = fp16(x @ W1), 64 rows x 128 cols ----
    f16* Ash = (f16*)smem;                         // [64][136]
    f16* Bsh = Ash + 64 * 136;                     // [128][136]
    int row0 = (blockIdx.x - NBUCK) << 6;

    #pragma unroll
    for (int c = 0; c < 8; ++c) {
        int l = c * 256 + t;
        int r = l >> 5, f = l & 31;
        int rr = row0 + r;
        float4 v = {0.f, 0.f, 0.f, 0.f};
        if (rr < N) v = *(const float4*)&x[(size_t)rr * 128 + f * 4];
        half4 hv = {(f16)v.x, (f16)v.y, (f16)v.z, (f16)v.w};
        *(half4*)&Ash[r * 136 + f * 4] = hv;
    }
    #pragma unroll
    for (int c = 0; c < 8; ++c) {
        int l = c * 256 + t;
        int row = l >> 4, f = l & 15;
        *(half8*)&Bsh[row * 136 + f * 8] = *(const half8*)&W1t[row * 128 + f * 8];
    }
    __syncthreads();

    int lane = t & 63, w = t >> 6;
    int lr = lane & 15, kg = lane >> 4;
    f32x4 acc[8];
    #pragma unroll
    for (int ct = 0; ct < 8; ++ct) acc[ct] = (f32x4){0.f, 0.f, 0.f, 0.f};

    #pragma unroll
    for (int kt = 0; kt < 4; ++kt) {
        half8 af = *(const half8*)&Ash[(w * 16 + lr) * 136 + kt * 32 + kg * 8];
        #pragma unroll
        for (int ct = 0; ct < 8; ++ct) {
            half8 bf = *(const half8*)&Bsh[(ct * 16 + lr) * 136 + kt * 32 + kg * 8];
            acc[ct] = __builtin_amdgcn_mfma_f32_16x16x32_f16(af, bf, acc[ct], 0, 0, 0);
        }
    }

    #pragma unroll
    for (int reg = 0; reg < 4; ++reg) {
        float ps0 = 0.f, pd0 = 0.f, ps1 = 0.f, pd1 = 0.f;
        #pragma unroll
        for (int ct = 0; ct < 4; ++ct) {
            float a = acc[ct][reg];
            ps0 += a * a1s_vec[ct * 16 + lr];
            pd0 += a * a1d_vec[ct * 16 + lr];
        }
        #pragma unroll
        for (int ct = 4; ct < 8; ++ct) {
            float a = acc[ct][reg];
            ps1 += a * a1s_vec[ct * 16 + lr];
            pd1 += a * a1d_vec[ct * 16 + lr];
        }
        #pragma unroll
        for (int o = 1; o <= 8; o <<= 1) {
            ps0 += __shfl_xor(ps0, o); pd0 += __shfl_xor(pd0, o);
            ps1 += __shfl_xor(ps1, o); pd1 += __shfl_xor(pd1, o);
        }
        if (lr == 0) {
            int rr = row0 + w * 16 + kg * 4 + reg;
            if (rr < N) {
                a1s[rr * 2] = ps0; a1d[rr * 2] = pd0;
                a1s[rr * 2 + 1] = ps1; a1d[rr * 2 + 1] = pd1;
            }
        }
    }

    __syncthreads();
    #pragma unroll
    for (int ct = 0; ct < 8; ++ct)
        #pragma unroll
        for (int reg = 0; reg < 4; ++reg)
            Ash[(w * 16 + kg * 4 + reg) * 136 + ct * 16 + lr] = (f16)acc[ct][reg];
    __syncthreads();
    #pragma unroll
    for (int c = 0; c < 4; ++c) {
        int l = c * 256 + t;
        int r = l >> 4, f = l & 15;
        int rr = row0 + r;
        if (rr < N) *(half8*)&h1h[(size_t)rr * 128 + f * 8] = *(const half8*)&Ash[r * 136 + f * 8];
    }
}

// ============================ Fused softmax+aggregate, layer 1 ============================
__global__ __launch_bounds__(256) void fused_aggr1(
    const int* __restrict__ rowStart, const int* __restrict__ deg, const int* __restrict__ srcS,
    const float* __restrict__ a1s, const float* __restrict__ a1d, const float* __restrict__ b1,
    const f16* __restrict__ h1h, f16* __restrict__ out1h, int N)
{
    int lane = threadIdx.x & 63;
    int dst = blockIdx.x * 4 + (threadIdx.x >> 6);
    if (dst >= N) return;
    int base = rowStart[dst];
    int d = deg[dst];
    float ad0 = a1d[2 * dst], ad1 = a1d[2 * dst + 1];
    int tx = lane & 15, j2 = lane >> 4;
    float acc[8] = {};
    float dpart0 = 0.f, dpart1 = 0.f;

    for (int c0 = 0; c0 < d; c0 += 64) {
        int cn = min(64, d - c0);
        int s = 0; float p0 = 0.f, p1 = 0.f;
        if (lane < cn) {
            s = srcS[base + c0 + lane];
            float2 av = *(const float2*)&a1s[2 * s];
            float e0 = av.x + ad0, e1 = av.y + ad1;
            e0 = e0 > 0.f ? e0 : NEG_SLOPE * e0;
            e1 = e1 > 0.f ? e1 : NEG_SLOPE * e1;
            p0 = __expf(e0); p1 = __expf(e1);
        }
        dpart0 += p0; dpart1 += p1;
        int niter = (cn + 3) >> 2;
        #pragma unroll 4
        for (int jj = 0; jj < niter; ++jj) {
            int esub = jj * 4 + j2;
            int   sj = __shfl(s, esub);
            float q0 = __shfl(p0, esub);
            float q1 = __shfl(p1, esub);
            float q  = (tx < 8) ? q0 : q1;
            half8 v = *(const half8*)&h1h[(size_t)sj * 128 + tx * 8];
            #pragma unroll
            for (int k = 0; k < 8; ++k) acc[k] += q * (float)v[k];
        }
    }
    #pragma unroll
    for (int k = 0; k < 8; ++k) acc[k] += __shfl_xor(acc[k], 16);
    #pragma unroll
    for (int k = 0; k < 8; ++k) acc[k] += __shfl_xor(acc[k], 32);
    #pragma unroll
    for (int o = 32; o; o >>= 1) { dpart0 += __shfl_xor(dpart0, o); dpart1 += __shfl_xor(dpart1, o); }
    if (j2 == 0) {
        float iv = (tx < 8) ? (1.f / dpart0) : (1.f / dpart1);
        float4 blo = *(const float4*)&b1[tx * 8];
        float4 bhi = *(const float4*)&b1[tx * 8 + 4];
        float o0 = fmaxf(acc[0] * iv + blo.x, 0.f);
        float o1 = fmaxf(acc[1] * iv + blo.y, 0.f);
        float o2 = fmaxf(acc[2] * iv + blo.z, 0.f);
        float o3 = fmaxf(acc[3] * iv + blo.w, 0.f);
        float o4 = fmaxf(acc[4] * iv + bhi.x, 0.f);
        float o5 = fmaxf(acc[5] * iv + bhi.y, 0.f);
        float o6 = fmaxf(acc[6] * iv + bhi.z, 0.f);
        float o7 = fmaxf(acc[7] * iv + bhi.w, 0.f);
        half8 hv = {(f16)o0, (f16)o1, (f16)o2, (f16)o3, (f16)o4, (f16)o5, (f16)o6, (f16)o7};
        *(half8*)&out1h[(size_t)dst * 128 + tx * 8] = hv;
    }
}

// ============================ GEMM 2 (MFMA) ============================
__global__ __launch_bounds__(256) void gemm2_kernel(
    const f16* __restrict__ out1h, const f16* __restrict__ W2t,
    const float* __restrict__ a2s_vec, const float* __restrict__ a2d_vec,
    f16* __restrict__ h2h, float* __restrict__ a2s, float* __restrict__ a2d, int N)
{
    __shared__ f16 Ash[64 * 136];
    __shared__ f16 Bsh[64 * 136];
    int t = threadIdx.x;
    int row0 = blockIdx.x << 6;

    #pragma unroll
    for (int c = 0; c < 4; ++c) {
        int l = c * 256 + t;
        int r = l >> 4, f = l & 15;
        int rr = row0 + r;
        half8 hv = {0, 0, 0, 0, 0, 0, 0, 0};
        if (rr < N) hv = *(const half8*)&out1h[(size_t)rr * 128 + f * 8];
        *(half8*)&Ash[r * 136 + f * 8] = hv;
    }
    #pragma unroll
    for (int c = 0; c < 4; ++c) {
        int l = c * 256 + t;
        int row = l >> 4, f = l & 15;
        *(half8*)&Bsh[row * 136 + f * 8] = *(const half8*)&W2t[row * 128 + f * 8];
    }
    __syncthreads();

    int lane = t & 63, w = t >> 6;
    int lr = lane & 15, kg = lane >> 4;
    f32x4 acc[4];
    #pragma unroll
    for (int ct = 0; ct < 4; ++ct) acc[ct] = (f32x4){0.f, 0.f, 0.f, 0.f};

    #pragma unroll
    for (int kt = 0; kt < 4; ++kt) {
        half8 af = *(const half8*)&Ash[(w * 16 + lr) * 136 + kt * 32 + kg * 8];
        #pragma unroll
        for (int ct = 0; ct < 4; ++ct) {
            half8 bf = *(const half8*)&Bsh[(ct * 16 + lr) * 136 + kt * 32 + kg * 8];
            acc[ct] = __builtin_amdgcn_mfma_f32_16x16x32_f16(af, bf, acc[ct], 0, 0, 0);
        }
    }

    #pragma unroll
    for (int reg = 0; reg < 4; ++reg) {
        float ps = 0.f, pd = 0.f;
        #pragma unroll
        for (int ct = 0; ct < 4; ++ct) {
            float a = acc[ct][reg];
            ps += a * a2s_vec[ct * 16 + lr];
            pd += a * a2d_vec[ct * 16 + lr];
        }
        #pragma unroll
        for (int o = 1; o <= 8; o <<= 1) { ps += __shfl_xor(ps, o); pd += __shfl_xor(pd, o); }
        if (lr == 0) {
            int rr = row0 + w * 16 + kg * 4 + reg;
            if (rr < N) { a2s[rr] = ps; a2d[rr] = pd; }
        }
    }

    __syncthreads();
    #pragma unroll
    for (int ct = 0; ct < 4; ++ct)
        #pragma unroll
        for (int reg = 0; reg < 4; ++reg)
            Ash[(w * 16 + kg * 4 + reg) * 136 + ct * 16 + lr] = (f16)acc[ct][reg];
    __syncthreads();
    #pragma unroll
    for (int c = 0; c < 2; ++c) {
        int l = c * 256 + t;
        int r = l >> 3, f = l & 7;
        int rr = row0 + r;
        if (rr < N) *(half8*)&h2h[(size_t)rr * 64 + f * 8] = *(const half8*)&Ash[r * 136 + f * 8];
    }
}

// ============================ Fused softmax+aggregate, layer 2 ============================
// Epilogue applies b2+relu, stores fp16 (out2h). NO per-node atomics (round-12 lesson).
__global__ __launch_bounds__(256) void fused_aggr2(
    const int* __restrict__ rowStart, const int* __restrict__ deg, const int* __restrict__ srcS,
    const float* __restrict__ a2s, const float* __restrict__ a2d, const float* __restrict__ b2,
    const f16* __restrict__ h2h, f16* __restrict__ out2h, int N)
{
    int lane = threadIdx.x & 63;
    int dst = blockIdx.x * 4 + (threadIdx.x >> 6);
    if (dst >= N) return;
    int base = rowStart[dst];
    int d = deg[dst];
    float ad = a2d[dst];
    int tx = lane & 7, j3 = lane >> 3;
    float acc[8] = {};
    float dpart = 0.f;

    for (int c0 = 0; c0 < d; c0 += 64) {
        int cn = min(64, d - c0);
        int s = 0; float p = 0.f;
        if (lane < cn) {
            s = srcS[base + c0 + lane];
            float e = a2s[s] + ad;
            e = e > 0.f ? e : NEG_SLOPE * e;
            p = __expf(e);
        }
        dpart += p;
        int niter = (cn + 7) >> 3;
        #pragma unroll 4
        for (int jj = 0; jj < niter; ++jj) {
            int esub = jj * 8 + j3;
            int   sj = __shfl(s, esub);
            float q  = __shfl(p, esub);
            half8 v = *(const half8*)&h2h[(size_t)sj * 64 + tx * 8];
            #pragma unroll
            for (int k = 0; k < 8; ++k) acc[k] += q * (float)v[k];
        }
    }
    #pragma unroll
    for (int k = 0; k < 8; ++k) acc[k] += __shfl_xor(acc[k], 8);
    #pragma unroll
    for (int k = 0; k < 8; ++k) acc[k] += __shfl_xor(acc[k], 16);
    #pragma unroll
    for (int k = 0; k < 8; ++k) acc[k] += __shfl_xor(acc[k], 32);
    #pragma unroll
    for (int o = 32; o; o >>= 1) dpart += __shfl_xor(dpart, o);
    if (j3 == 0) {
        float iv = 1.f / dpart;
        float4 blo = *(const float4*)&b2[tx * 8];
        float4 bhi = *(const float4*)&b2[tx * 8 + 4];
        float o0 = fmaxf(acc[0] * iv + blo.x, 0.f);
        float o1 = fmaxf(acc[1] * iv + blo.y, 0.f);
        float o2 = fmaxf(acc[2] * iv + blo.z, 0.f);
        float o3 = fmaxf(acc[3] * iv + blo.w, 0.f);
        float o4 = fmaxf(acc[4] * iv + bhi.x, 0.f);
        float o5 = fmaxf(acc[5] * iv + bhi.y, 0.f);
        float o6 = fmaxf(acc[6] * iv + bhi.z, 0.f);
        float o7 = fmaxf(acc[7] * iv + bhi.w, 0.f);
        half8 hv = {(f16)o0, (f16)o1, (f16)o2, (f16)o3, (f16)o4, (f16)o5, (f16)o6, (f16)o7};
        *(half8*)&out2h[(size_t)dst * 64 + tx * 8] = hv;
    }
}

// ============================ Pool: register-range accumulation ============================
__global__ __launch_bounds__(256) void pool_kernel(
    const f16* __restrict__ out2h, const int* __restrict__ batch,
    float* __restrict__ pool, float* __restrict__ cnt, int N)
{
    int lane = threadIdx.x & 63;
    int gwave = blockIdx.x * 4 + (threadIdx.x >> 6);
    int nwaves = gridDim.x * 4;
    int per = (N + nwaves - 1) / nwaves;
    int n0 = gwave * per;
    int n1 = min(n0 + per, N);
    if (n0 >= n1) return;
    float acc = 0.f;
    int count = 0;
    int gcur = batch[n0];
    for (int n = n0; n < n1; ++n) {
        int g = batch[n];
        if (g != gcur) {
            atomicAdd(&pool[gcur * 64 + lane], acc);
            if (lane == 0) atomicAdd(&cnt[gcur], (float)count);
            acc = 0.f; count = 0; gcur = g;
        }
        acc += (float)out2h[(size_t)n * 64 + lane];
        ++count;
    }
    atomicAdd(&pool[gcur * 64 + lane], acc);
    if (lane == 0) atomicAdd(&cnt[gcur], (float)count);
}

// ============================ Final linear ============================
__global__ void final_kernel(
    const float* __restrict__ pool, const float* __restrict__ cnt,
    const float* __restrict__ Wlin, const float* __restrict__ blin,
    float* __restrict__ out, int G)
{
    int g = threadIdx.x;
    if (g >= G) return;
    float s = 0.f;
    #pragma unroll 8
    for (int c = 0; c < 64; ++c) s += pool[g * 64 + c] * Wlin[c];
    float cn = cnt[g]; cn = cn > 1.f ? cn : 1.f;
    out[g] = s / cn + blin[0];
}

extern "C" void kernel_launch(void* const* d_in, const int* in_sizes, int n_in,
                              void* d_out, int out_size, void* d_ws, size_t ws_size,
                              hipStream_t stream) {
    const float* x     = (const float*)d_in[0];
    const int*   ei    = (const int*)d_in[1];
    const int*   batch = (const int*)d_in[2];
    const float* W1    = (const float*)d_in[3];
    const float* a1sv  = (const float*)d_in[4];
    const float* a1dv  = (const float*)d_in[5];
    const float* b1    = (const float*)d_in[6];
    const float* W2    = (const float*)d_in[7];
    const float* a2sv  = (const float*)d_in[8];
    const float* a2dv  = (const float*)d_in[9];
    const float* b2    = (const float*)d_in[10];
    const float* Wlin  = (const float*)d_in[11];
    const float* blin  = (const float*)d_in[12];

    int N  = in_sizes[2];
    int E  = in_sizes[1] / 2;
    int Ep = E + N;
    const int G = 64;
    int chunk = (Ep + NB1 - 1) / NB1;

    float* ws = (float*)d_ws;
    size_t off = 0;
    f16*  out1h = (f16*)(ws + off); off += (size_t)N * 64;   // N*128 halves
    f16*  h1h   = (f16*)(ws + off); off += (size_t)N * 64;   // N*128 halves
    f16*  h2h   = (f16*)(ws + off); off += (size_t)N * 32;   // N*64 halves
    float* a1s  = ws + off; off += (size_t)N * 2;
    float* a1d  = ws + off; off += (size_t)N * 2;
    float* a2s  = ws + off; off += N;
    float* a2d  = ws + off; off += N;
    int* degA   = (int*)(ws + off); off += N;
    int* rowStart = (int*)(ws + off); off += N;
    int* cntg   = (int*)(ws + off); off += NB1 * NBUCK;
    int* offs   = (int*)(ws + off); off += NB1 * NBUCK;
    int* tot    = (int*)(ws + off); off += NBUCK;
    unsigned* pairs = (unsigned*)(ws + off); off += Ep;
    int* srcS   = (int*)(ws + off); off += Ep;
    float* pool = ws + off; off += G * 64;
    float* cnt  = ws + off; off += G;
    f16* W1t    = (f16*)(ws + off); off += 128 * 64;         // 128*128 halves
    f16* W2t    = (f16*)(ws + off); off += 64 * 64;          // 64*128 halves
    f16* out2h  = h1h;   // alias: h1h dead after fused_aggr1

    // A: W transposes ∥ bucket histogram ∥ zero pool+cnt (contiguous, G*64+G floats)
    kernelA<<<96 + NB1, 256, 0, stream>>>(W1, W2, W1t, W2t, ei, cntg, pool, G * 64 + G, E, Ep, chunk);
    bucket_scan_t<<<NBUCK, 256, 0, stream>>>(cntg, offs, tot);
    bucket_place<<<NB1, 256, 0, stream>>>(ei, offs, tot, pairs, E, Ep, chunk);
    // B: CSR finalize (blocks 0..255) ∥ gemm1 (rest)
    kernelB<<<NBUCK + (N + 63) / 64, 256, 0, stream>>>(
        pairs, tot, rowStart, degA, srcS,
        x, W1t, a1sv, a1dv, h1h, a1s, a1d, N);
    fused_aggr1<<<(N + 3) / 4, 256, 0, stream>>>(rowStart, degA, srcS, a1s, a1d, b1, h1h, out1h, N);
    gemm2_kernel<<<(N + 63) / 64, 256, 0, stream>>>(out1h, W2t, a2sv, a2dv, h2h, a2s, a2d, N);
    fused_aggr2<<<(N + 3) / 4, 256, 0, stream>>>(rowStart, degA, srcS, a2s, a2d, b2, h2h, out2h, N);
    pool_kernel<<<256, 256, 0, stream>>>(out2h, batch, pool, cnt, N);
    final_kernel<<<1, 64, 0, stream>>>(pool, cnt, Wlin, blin, (float*)d_out, G);
}